// Round 12
// baseline (796.729 us; speedup 1.0000x reference)
//
#include <hip/hip_runtime.h>
#include <math.h>

#define NN 50000
#define NE 600000
#define DD 128
#define NL 4
#define NG 512
#define NT 10
#define EPSF 1e-5f

typedef __bf16 bf16x8 __attribute__((ext_vector_type(8)));
typedef float f32x4 __attribute__((ext_vector_type(4)));

__device__ __forceinline__ unsigned short f2bf(float x) {
    union { float f; unsigned u; } v; v.f = x;
    unsigned r = v.u + 0x7FFFu + ((v.u >> 16) & 1u);
    return (unsigned short)(r >> 16);
}
__device__ __forceinline__ unsigned pack_bf2(float a, float b) {
    return (unsigned)f2bf(a) | ((unsigned)f2bf(b) << 16);
}
__device__ __forceinline__ float bf_lo(unsigned v) {
    union { unsigned u; float f; } w; w.u = (v & 0xFFFFu) << 16; return w.f;
}
__device__ __forceinline__ float bf_hi(unsigned v) {
    union { unsigned u; float f; } w; w.u = v & 0xFFFF0000u; return w.f;
}

// ---------------- CSR build ----------------
__global__ void k_count(const int* __restrict__ dst, int* __restrict__ deg,
                        float* __restrict__ dsum, int E) {
    int e = blockIdx.x * blockDim.x + threadIdx.x;
    if (e == 0) *dsum = 0.f;
    if (e < E) atomicAdd(&deg[dst[e]], 1);
}

__global__ void k_scan_part(const int* __restrict__ deg, int* __restrict__ part, int n) {
    __shared__ int sm[256];
    int b = blockIdx.x, t = threadIdx.x;
    int base = b * 1024 + t * 4;
    int s = 0;
    #pragma unroll
    for (int j = 0; j < 4; j++) if (base + j < n) s += deg[base + j];
    sm[t] = s;
    __syncthreads();
    for (int off = 128; off > 0; off >>= 1) {
        if (t < off) sm[t] += sm[t + off];
        __syncthreads();
    }
    if (t == 0) part[b] = sm[0];
}

__global__ void k_scan_top(const int* __restrict__ part, int* __restrict__ offs,
                           int* __restrict__ row_ptr, int nb, int n) {
    if (threadIdx.x == 0) {
        int acc = 0;
        for (int i = 0; i < nb; i++) { offs[i] = acc; acc += part[i]; }
        row_ptr[n] = acc;
    }
}

__global__ void k_scan_apply(const int* __restrict__ deg, const int* __restrict__ offs,
                             int* __restrict__ row_ptr, int* __restrict__ cursor, int n) {
    __shared__ int sm[256];
    int b = blockIdx.x, t = threadIdx.x;
    int base = b * 1024 + t * 4;
    int v[4]; int s = 0;
    #pragma unroll
    for (int j = 0; j < 4; j++) { v[j] = (base + j < n) ? deg[base + j] : 0; s += v[j]; }
    sm[t] = s;
    __syncthreads();
    for (int off = 1; off < 256; off <<= 1) {
        int y = (t >= off) ? sm[t - off] : 0;
        __syncthreads();
        sm[t] += y;
        __syncthreads();
    }
    int run = offs[b] + sm[t] - s;
    #pragma unroll
    for (int j = 0; j < 4; j++) {
        if (base + j < n) { row_ptr[base + j] = run; cursor[base + j] = run; run += v[j]; }
    }
}

__global__ void k_fill(const int* __restrict__ src, const int* __restrict__ dst,
                       int* __restrict__ cursor, int* __restrict__ csr_src, int E) {
    int e = blockIdx.x * blockDim.x + threadIdx.x;
    if (e < E) {
        int d = dst[e];
        int pos = atomicAdd(&cursor[d], 1);
        csr_src[pos] = src[e];
    }
}

// ---------------- degree scalars ----------------
__global__ void k_delta(const int* __restrict__ deg, float* __restrict__ dsum, int n) {
    int i = blockIdx.x * blockDim.x + threadIdx.x;
    float v = (i < n) ? log1pf((float)deg[i]) : 0.f;
    #pragma unroll
    for (int off = 32; off > 0; off >>= 1) v += __shfl_down(v, off);
    if ((threadIdx.x & 63) == 0) atomicAdd(dsum, v);
}

__global__ void k_scalars(const int* __restrict__ deg, const float* __restrict__ dsum,
                          float* __restrict__ inv_d, float* __restrict__ amp,
                          float* __restrict__ att, int n) {
    int i = blockIdx.x * blockDim.x + threadIdx.x;
    if (i >= n) return;
    float delta = *dsum / (float)n;
    float d = fmaxf((float)deg[i], 1.f);
    float ld = log1pf(d);
    inv_d[i] = 1.f / d;
    amp[i] = ld / delta;
    att[i] = delta / ld;
}

// ---------------- node embedding (bf16 h) + per-layer BN accumulator zeroing ---------
__global__ void k_emb(const float* __restrict__ x, const float* __restrict__ W,
                      const float* __restrict__ b, unsigned* __restrict__ hb2,
                      float* __restrict__ bn_all, int total2) {
    int i = blockIdx.x * blockDim.x + threadIdx.x;
    if (blockIdx.x == 0) {   // zero bn_sum/bn_sq for all 4 layers (1024 floats)
        #pragma unroll
        for (int p = 0; p < 4; p++) bn_all[threadIdx.x + p * 256] = 0.f;
    }
    if (i >= total2) return;
    int node = i >> 6, c = (i & 63) * 2;
    float x0 = x[node * 3 + 0], x1 = x[node * 3 + 1], x2 = x[node * 3 + 2];
    float v0 = x0 * W[c] + x1 * W[DD + c] + x2 * W[2 * DD + c] + b[c];
    float v1 = x0 * W[c + 1] + x1 * W[DD + c + 1] + x2 * W[2 * DD + c + 1] + b[c + 1];
    hb2[i] = pack_bf2(v0, v1);
}

// -------- weight convert: conv_W [L,1536,128] f32 -> Bt2 [L][64 kc][3 j][128 col][8] bf16 ----
__global__ void k_wconv(const float* __restrict__ W, unsigned short* __restrict__ Bt2, int total) {
    int o = blockIdx.x * blockDim.x + threadIdx.x;
    if (o >= total) return;
    int l = o / 196608;
    int idx = o % 196608;
    int kc = idx / 3072;
    int rem = idx % 3072;
    int j = rem >> 10;
    int nn = (rem >> 3) & 127;
    int k8 = rem & 7;
    int k = kc * 8 + k8;
    Bt2[o] = f2bf(W[(size_t)l * 196608 + (size_t)(j * 512 + k) * 128 + nn]);
}

// ============ FUSED agg + GEMM (one dispatch per layer) ============
// Phase 1: each block aggregates 64 nodes (wave w -> nodes [16w,16w+16), x4 edge ILP)
//   into LDS sA[kc 0..63][stride 260 words]: kc = sec*16 + (t>>2), word = nl*4 + (t&3).
//   Bank = (4*(t>>2)+(t&3)) mod 32 = t mod 32 -> 2-way aliasing (free, m136).
// Phase 2 (v9-shape, proven best intensity): wave w owns 64 rows x 32 cols (c0=w*32),
//   24 MFMA/iter. A via ds_read_b128 from sA (low-latency, lgkmcnt fine-grained);
//   B (393 KB/layer, L2-resident) via register ping-pong, 1 iter ahead.
//   acc 96 AGPR + ~90 arch VGPR -> 2 waves/SIMD (launch_bounds(256,2); LDS 66.6KB -> 2 blk/CU).
// One barrier per block. Gather-phase (latency-bound) and gemm-phase (MFMA-bound) of
// co-resident blocks overlap (m114). Eliminates the 51+51 MB At round-trip per layer.
__global__ __launch_bounds__(256, 2) void k_agg_gemm(
    const unsigned* __restrict__ hb2, const int* __restrict__ row_ptr,
    const int* __restrict__ csr_src, const float* __restrict__ inv_d,
    const unsigned short* __restrict__ Bt2, const float* __restrict__ bias,
    const float* __restrict__ amp, const float* __restrict__ att,
    float* __restrict__ outp, float* __restrict__ bn_sum, float* __restrict__ bn_sq, int n) {
    __shared__ unsigned sA[64 * 260];       // [kc][260 words]; 66560 B
    int tid = threadIdx.x;
    int w = tid >> 6, t = tid & 63;
    int quad = t >> 4, l16 = t & 15;
    int node0 = blockIdx.x * 64;

    // ---------- phase 1: aggregate ----------
    int cw = t >> 2, co = t & 3;            // chunk-in-section, word-in-chunk
    #pragma unroll 1
    for (int q = 0; q < 16; q++) {
        int nl = w * 16 + q;
        int node = node0 + nl;
        int beg = 0, end = 0;
        if (node < n) { beg = row_ptr[node]; end = row_ptr[node + 1]; }
        float s1a = 0.f, s1b = 0.f, s2a = 0.f, s2b = 0.f;
        float mna = INFINITY, mnb = INFINITY, mxa = -INFINITY, mxb = -INFINITY;
        int e = beg;
        for (; e + 3 < end; e += 4) {       // 4 independent gathers in flight
            int sa = csr_src[e],     sb = csr_src[e + 1];
            int sc = csr_src[e + 2], sd = csr_src[e + 3];
            unsigned va = hb2[(size_t)sa * 64 + t];
            unsigned vb = hb2[(size_t)sb * 64 + t];
            unsigned vc = hb2[(size_t)sc * 64 + t];
            unsigned vd = hb2[(size_t)sd * 64 + t];
            float a0 = bf_lo(va), b0 = bf_hi(va);
            float a1 = bf_lo(vb), b1 = bf_hi(vb);
            float a2 = bf_lo(vc), b2 = bf_hi(vc);
            float a3 = bf_lo(vd), b3 = bf_hi(vd);
            s1a += (a0 + a1) + (a2 + a3);
            s2a += a0 * a0 + a1 * a1 + a2 * a2 + a3 * a3;
            mna = fminf(fminf(mna, fminf(a0, a1)), fminf(a2, a3));
            mxa = fmaxf(fmaxf(mxa, fmaxf(a0, a1)), fmaxf(a2, a3));
            s1b += (b0 + b1) + (b2 + b3);
            s2b += b0 * b0 + b1 * b1 + b2 * b2 + b3 * b3;
            mnb = fminf(fminf(mnb, fminf(b0, b1)), fminf(b2, b3));
            mxb = fmaxf(fmaxf(mxb, fmaxf(b0, b1)), fmaxf(b2, b3));
        }
        for (; e < end; e++) {
            int sa = csr_src[e];
            unsigned va = hb2[(size_t)sa * 64 + t];
            float a0 = bf_lo(va), b0 = bf_hi(va);
            s1a += a0; s2a += a0 * a0; mna = fminf(mna, a0); mxa = fmaxf(mxa, a0);
            s1b += b0; s2b += b0 * b0; mnb = fminf(mnb, b0); mxb = fmaxf(mxb, b0);
        }
        float id = (node < n) ? inv_d[node] : 1.f;
        float meana = s1a * id, meanb = s1b * id;
        float sda = sqrtf(fmaxf(s2a * id - meana * meana, 0.f) + EPSF);
        float sdb = sqrtf(fmaxf(s2b * id - meanb * meanb, 0.f) + EPSF);
        if (beg == end) { mna = 0.f; mxa = 0.f; mnb = 0.f; mxb = 0.f; }
        int wbase = nl * 4 + co;
        sA[(0 * 16 + cw) * 260 + wbase] = pack_bf2(meana, meanb);
        sA[(1 * 16 + cw) * 260 + wbase] = pack_bf2(mna, mnb);
        sA[(2 * 16 + cw) * 260 + wbase] = pack_bf2(mxa, mxb);
        sA[(3 * 16 + cw) * 260 + wbase] = pack_bf2(sda, sdb);
    }
    __syncthreads();

    // ---------- phase 2: GEMM ----------
    int c0 = w * 32;
    f32x4 acc[4][2][3];
    #pragma unroll
    for (int rt = 0; rt < 4; rt++)
        #pragma unroll
        for (int ct = 0; ct < 2; ct++)
            #pragma unroll
            for (int j = 0; j < 3; j++) acc[rt][ct][j] = (f32x4)(0.f);

    const unsigned short* pB = Bt2 + ((size_t)quad * 384 + c0 + l16) * 8;
    const int stepB = 4 * 384 * 8;
    bf16x8 bf0[2][3], bf1[2][3];
    auto loadB = [&](bf16x8 (*dst)[3]) {
        #pragma unroll
        for (int ct = 0; ct < 2; ct++)
            #pragma unroll
            for (int j = 0; j < 3; j++)
                dst[ct][j] = *(const bf16x8*)(pB + j * 1024 + ct * 128);
        pB += stepB;
    };
    auto step = [&](int it, bf16x8 (*bf)[3]) {
        bf16x8 af[4];
        int kc = it * 4 + quad;
        #pragma unroll
        for (int rt = 0; rt < 4; rt++)
            af[rt] = *(const bf16x8*)&sA[kc * 260 + (rt * 16 + l16) * 4];
        #pragma unroll
        for (int ct = 0; ct < 2; ct++)
            #pragma unroll
            for (int j = 0; j < 3; j++)
                #pragma unroll
                for (int rt = 0; rt < 4; rt++)
                    acc[rt][ct][j] = __builtin_amdgcn_mfma_f32_16x16x32_bf16(
                        af[rt], bf[ct][j], acc[rt][ct][j], 0, 0, 0);
    };

    loadB(bf0);
    #pragma unroll 1
    for (int it = 0; it < 16; it += 2) {
        loadB(bf1);                  // prefetch iter it+1 (tail: pad read, unused)
        step(it, bf0);
        loadB(bf0);                  // prefetch iter it+2 (tail: pad read, unused)
        step(it + 1, bf1);
    }

    // epilogue: combine j via amp/att, bias, write, BN partials
    float psum[2] = {0.f, 0.f}, psq[2] = {0.f, 0.f};
    #pragma unroll
    for (int rt = 0; rt < 4; rt++) {
        #pragma unroll
        for (int reg = 0; reg < 4; reg++) {
            int row = node0 + rt * 16 + quad * 4 + reg;
            if (row < n) {
                float am = amp[row], at = att[row];
                #pragma unroll
                for (int ct = 0; ct < 2; ct++) {
                    int col = c0 + ct * 16 + l16;
                    float v = acc[rt][ct][0][reg] + am * acc[rt][ct][1][reg]
                            + at * acc[rt][ct][2][reg] + bias[col];
                    outp[(size_t)row * DD + col] = v;
                    psum[ct] += v;
                    psq[ct] += v * v;
                }
            }
        }
    }
    #pragma unroll
    for (int ct = 0; ct < 2; ct++) {
        psum[ct] += __shfl_xor(psum[ct], 16, 64);
        psum[ct] += __shfl_xor(psum[ct], 32, 64);
        psq[ct]  += __shfl_xor(psq[ct], 16, 64);
        psq[ct]  += __shfl_xor(psq[ct], 32, 64);
    }
    if (quad == 0) {
        #pragma unroll
        for (int ct = 0; ct < 2; ct++) {
            int col = c0 + ct * 16 + l16;
            atomicAdd(&bn_sum[col], psum[ct]);
            atomicAdd(&bn_sq[col], psq[ct]);
        }
    }
}

// ------- BN stats+apply+relu+residual (bf16 h state; 8 channels/thread) --------
__global__ void k_bnapply(const float* __restrict__ outp, const float* __restrict__ bn_sum,
                          const float* __restrict__ bn_sq, const float* __restrict__ gamma,
                          const float* __restrict__ beta, unsigned* __restrict__ hb2,
                          int total8) {
    int i = blockIdx.x * blockDim.x + threadIdx.x;
    if (i >= total8) return;
    int c = (i & 15) * 8;
    const float invn = 1.f / (float)NN;
    float4 o0 = ((const float4*)outp)[i * 2];
    float4 o1 = ((const float4*)outp)[i * 2 + 1];
    uint4 hv = ((const uint4*)hb2)[i];
    float oo[8] = {o0.x, o0.y, o0.z, o0.w, o1.x, o1.y, o1.z, o1.w};
    unsigned hu[4] = {hv.x, hv.y, hv.z, hv.w};
    unsigned ru[4];
    #pragma unroll
    for (int p = 0; p < 4; p++) {
        int c0 = c + p * 2;
        float mu0 = bn_sum[c0] * invn;
        float var0 = bn_sq[c0] * invn - mu0 * mu0;
        float sc0 = rsqrtf(var0 + EPSF) * gamma[c0];
        float sh0 = beta[c0] - mu0 * sc0;
        float mu1 = bn_sum[c0 + 1] * invn;
        float var1 = bn_sq[c0 + 1] * invn - mu1 * mu1;
        float sc1 = rsqrtf(var1 + EPSF) * gamma[c0 + 1];
        float sh1 = beta[c0 + 1] - mu1 * sc1;
        float v0 = fmaxf(oo[p * 2] * sc0 + sh0, 0.f) + bf_lo(hu[p]);
        float v1 = fmaxf(oo[p * 2 + 1] * sc1 + sh1, 0.f) + bf_hi(hu[p]);
        ru[p] = pack_bf2(v0, v1);
    }
    ((uint4*)hb2)[i] = make_uint4(ru[0], ru[1], ru[2], ru[3]);
}

// ---------------- pool + MLP (bf16 h input) ----------------
__global__ void k_pool_mlp(const unsigned* __restrict__ hb2, const int* __restrict__ batch,
                           const float* __restrict__ W1, const float* __restrict__ b1,
                           const float* __restrict__ W2, const float* __restrict__ b2,
                           const float* __restrict__ W3, const float* __restrict__ b3,
                           float* __restrict__ out, int n) {
    __shared__ float gvec[128];
    __shared__ float h1[64];
    __shared__ float h2[32];
    __shared__ int srange[2];
    int g = blockIdx.x;
    int t = threadIdx.x;
    if (t < 2) {
        int target = g + t;
        int lo = 0, hi = n;
        while (lo < hi) {
            int mid = (lo + hi) >> 1;
            if (batch[mid] < target) lo = mid + 1; else hi = mid;
        }
        srange[t] = lo;
    }
    __syncthreads();
    int s = srange[0], e = srange[1];
    int p = t >> 1, odd = t & 1;
    float acc = 0.f;
    for (int i = s; i < e; i++) {
        unsigned v = hb2[(size_t)i * 64 + p];
        acc += odd ? bf_hi(v) : bf_lo(v);
    }
    float cnt = fmaxf((float)(e - s), 1.f);
    gvec[t] = acc / cnt;
    __syncthreads();
    if (t < 64) {
        float a = b1[t];
        for (int k = 0; k < 128; k++) a += gvec[k] * W1[k * 64 + t];
        h1[t] = fmaxf(a, 0.f);
    }
    __syncthreads();
    if (t < 32) {
        float a = b2[t];
        for (int k = 0; k < 64; k++) a += h1[k] * W2[k * 32 + t];
        h2[t] = fmaxf(a, 0.f);
    }
    __syncthreads();
    if (t < 10) {
        float a = b3[t];
        for (int k = 0; k < 32; k++) a += h2[k] * W3[k * 10 + t];
        out[g * NT + t] = a;
    }
}

extern "C" void kernel_launch(void* const* d_in, const int* in_sizes, int n_in,
                              void* d_out, int out_size, void* d_ws, size_t ws_size,
                              hipStream_t stream) {
    const float* x      = (const float*)d_in[0];
    const int*   eidx   = (const int*)d_in[1];
    const int*   batch  = (const int*)d_in[2];
    const float* emb_W  = (const float*)d_in[3];
    const float* emb_b  = (const float*)d_in[4];
    const float* conv_W = (const float*)d_in[5];
    const float* conv_b = (const float*)d_in[6];
    const float* bn_g   = (const float*)d_in[7];
    const float* bn_b   = (const float*)d_in[8];
    const float* W1 = (const float*)d_in[9];
    const float* b1 = (const float*)d_in[10];
    const float* W2 = (const float*)d_in[11];
    const float* b2 = (const float*)d_in[12];
    const float* W3 = (const float*)d_in[13];
    const float* b3 = (const float*)d_in[14];
    float* out = (float*)d_out;

    const int* src = eidx;
    const int* dst = eidx + NE;

    char* p = (char*)d_ws;
    auto carve = [&](size_t bytes) {
        void* r = (void*)p;
        p += (bytes + 255) & ~(size_t)255;
        return r;
    };
    int* deg      = (int*)carve(NN * 4);
    int* row_ptr  = (int*)carve((NN + 1) * 4);
    int* cursor   = (int*)carve(NN * 4);
    int* csr_src  = (int*)carve(NE * 4);
    int* part     = (int*)carve(64 * 4);
    int* offs     = (int*)carve(64 * 4);
    float* inv_d  = (float*)carve(NN * 4);
    float* amp    = (float*)carve(NN * 4);
    float* att    = (float*)carve(NN * 4);
    float* dsum   = (float*)carve(4);
    float* bn_all = (float*)carve(1024 * 4);   // [4 layers][sum 128 | padded] + [sq]
    unsigned* hb2 = (unsigned*)carve((size_t)NN * 64 * 4);
    float* outp   = (float*)carve((size_t)NN * DD * 4);
    unsigned short* Bt2 = (unsigned short*)carve(((size_t)NL * 196608 + 12288) * 2);

    float* bn_sum = bn_all;        // 4 x 128
    float* bn_sq  = bn_all + 512;  // 4 x 128

    hipMemsetAsync(deg, 0, NN * 4, stream);

    const int NSB = (NN + 1023) / 1024;   // 49 scan blocks
    k_count<<<(NE + 255) / 256, 256, 0, stream>>>(dst, deg, dsum, NE);
    k_scan_part<<<NSB, 256, 0, stream>>>(deg, part, NN);
    k_scan_top<<<1, 64, 0, stream>>>(part, offs, row_ptr, NSB, NN);
    k_scan_apply<<<NSB, 256, 0, stream>>>(deg, offs, row_ptr, cursor, NN);
    k_fill<<<(NE + 255) / 256, 256, 0, stream>>>(src, dst, cursor, csr_src, NE);
    k_delta<<<(NN + 255) / 256, 256, 0, stream>>>(deg, dsum, NN);
    k_scalars<<<(NN + 255) / 256, 256, 0, stream>>>(deg, dsum, inv_d, amp, att, NN);
    k_emb<<<(NN * 64 + 255) / 256, 256, 0, stream>>>(x, emb_W, emb_b, hb2, bn_all, NN * 64);
    k_wconv<<<(NL * 196608 + 255) / 256, 256, 0, stream>>>(conv_W, Bt2, NL * 196608);

    const int fused_blocks = (NN + 63) / 64;   // 782
    for (int l = 0; l < NL; l++) {
        k_agg_gemm<<<fused_blocks, 256, 0, stream>>>(
            hb2, row_ptr, csr_src, inv_d,
            Bt2 + (size_t)l * 196608, conv_b + l * DD, amp, att,
            outp, bn_sum + l * DD, bn_sq + l * DD, NN);
        k_bnapply<<<(NN * 16 + 255) / 256, 256, 0, stream>>>(
            outp, bn_sum + l * DD, bn_sq + l * DD,
            bn_g + l * DD, bn_b + l * DD, hb2, NN * 16);
    }

    k_pool_mlp<<<NG, 128, 0, stream>>>(hb2, batch, W1, b1, W2, b2, W3, b3, out, NN);
}

// Round 13
// 591.874 us; speedup vs baseline: 1.3461x; 1.3461x over previous
//
#include <hip/hip_runtime.h>
#include <math.h>

#define NN 50000
#define NE 600000
#define DD 128
#define NL 4
#define NG 512
#define NT 10
#define NPAD 50176          // 392 * 128, padded row count for A_t
#define EPSF 1e-5f

typedef __bf16 bf16x8 __attribute__((ext_vector_type(8)));
typedef float f32x4 __attribute__((ext_vector_type(4)));

__device__ __forceinline__ unsigned short f2bf(float x) {
    union { float f; unsigned u; } v; v.f = x;
    unsigned r = v.u + 0x7FFFu + ((v.u >> 16) & 1u);
    return (unsigned short)(r >> 16);
}
__device__ __forceinline__ unsigned pack_bf2(float a, float b) {
    return (unsigned)f2bf(a) | ((unsigned)f2bf(b) << 16);
}
__device__ __forceinline__ float bf_lo(unsigned v) {
    union { unsigned u; float f; } w; w.u = (v & 0xFFFFu) << 16; return w.f;
}
__device__ __forceinline__ float bf_hi(unsigned v) {
    union { unsigned u; float f; } w; w.u = v & 0xFFFF0000u; return w.f;
}

// ---------------- CSR build ----------------
__global__ void k_count(const int* __restrict__ dst, int* __restrict__ deg,
                        float* __restrict__ dsum, int E) {
    int e = blockIdx.x * blockDim.x + threadIdx.x;
    if (e == 0) *dsum = 0.f;
    if (e < E) atomicAdd(&deg[dst[e]], 1);
}

__global__ void k_scan_part(const int* __restrict__ deg, int* __restrict__ part, int n) {
    __shared__ int sm[256];
    int b = blockIdx.x, t = threadIdx.x;
    int base = b * 1024 + t * 4;
    int s = 0;
    #pragma unroll
    for (int j = 0; j < 4; j++) if (base + j < n) s += deg[base + j];
    sm[t] = s;
    __syncthreads();
    for (int off = 128; off > 0; off >>= 1) {
        if (t < off) sm[t] += sm[t + off];
        __syncthreads();
    }
    if (t == 0) part[b] = sm[0];
}

__global__ void k_scan_top(const int* __restrict__ part, int* __restrict__ offs,
                           int* __restrict__ row_ptr, int nb, int n) {
    if (threadIdx.x == 0) {
        int acc = 0;
        for (int i = 0; i < nb; i++) { offs[i] = acc; acc += part[i]; }
        row_ptr[n] = acc;
    }
}

__global__ void k_scan_apply(const int* __restrict__ deg, const int* __restrict__ offs,
                             int* __restrict__ row_ptr, int* __restrict__ cursor, int n) {
    __shared__ int sm[256];
    int b = blockIdx.x, t = threadIdx.x;
    int base = b * 1024 + t * 4;
    int v[4]; int s = 0;
    #pragma unroll
    for (int j = 0; j < 4; j++) { v[j] = (base + j < n) ? deg[base + j] : 0; s += v[j]; }
    sm[t] = s;
    __syncthreads();
    for (int off = 1; off < 256; off <<= 1) {
        int y = (t >= off) ? sm[t - off] : 0;
        __syncthreads();
        sm[t] += y;
        __syncthreads();
    }
    int run = offs[b] + sm[t] - s;
    #pragma unroll
    for (int j = 0; j < 4; j++) {
        if (base + j < n) { row_ptr[base + j] = run; cursor[base + j] = run; run += v[j]; }
    }
}

__global__ void k_fill(const int* __restrict__ src, const int* __restrict__ dst,
                       int* __restrict__ cursor, int* __restrict__ csr_src, int E) {
    int e = blockIdx.x * blockDim.x + threadIdx.x;
    if (e < E) {
        int d = dst[e];
        int pos = atomicAdd(&cursor[d], 1);
        csr_src[pos] = src[e];
    }
}

// ---------------- degree scalars ----------------
__global__ void k_delta(const int* __restrict__ deg, float* __restrict__ dsum, int n) {
    int i = blockIdx.x * blockDim.x + threadIdx.x;
    float v = (i < n) ? log1pf((float)deg[i]) : 0.f;
    #pragma unroll
    for (int off = 32; off > 0; off >>= 1) v += __shfl_down(v, off);
    if ((threadIdx.x & 63) == 0) atomicAdd(dsum, v);
}

__global__ void k_scalars(const int* __restrict__ deg, const float* __restrict__ dsum,
                          float* __restrict__ inv_d, float* __restrict__ amp,
                          float* __restrict__ att, int n) {
    int i = blockIdx.x * blockDim.x + threadIdx.x;
    if (i >= n) return;
    float delta = *dsum / (float)n;
    float d = fmaxf((float)deg[i], 1.f);
    float ld = log1pf(d);
    inv_d[i] = 1.f / d;
    amp[i] = ld / delta;
    att[i] = delta / ld;
}

// ---------------- node embedding (bf16 h only) ----------------
__global__ void k_emb(const float* __restrict__ x, const float* __restrict__ W,
                      const float* __restrict__ b, unsigned* __restrict__ hb2, int total2) {
    int i = blockIdx.x * blockDim.x + threadIdx.x;
    if (i >= total2) return;
    int node = i >> 6, c = (i & 63) * 2;
    float x0 = x[node * 3 + 0], x1 = x[node * 3 + 1], x2 = x[node * 3 + 2];
    float v0 = x0 * W[c] + x1 * W[DD + c] + x2 * W[2 * DD + c] + b[c];
    float v1 = x0 * W[c + 1] + x1 * W[DD + c + 1] + x2 * W[2 * DD + c + 1] + b[c + 1];
    hb2[i] = pack_bf2(v0, v1);
}

// -------- weight convert: conv_W [L,1536,128] f32 -> Bt2 [L][64 kc][3 j][128 col][8] bf16 ----
__global__ void k_wconv(const float* __restrict__ W, unsigned short* __restrict__ Bt2, int total) {
    int o = blockIdx.x * blockDim.x + threadIdx.x;
    if (o >= total) return;
    int l = o / 196608;
    int idx = o % 196608;
    int kc = idx / 3072;
    int rem = idx % 3072;
    int j = rem >> 10;
    int nn = (rem >> 3) & 127;
    int k8 = rem & 7;
    int k = kc * 8 + k8;
    Bt2[o] = f2bf(W[(size_t)l * 196608 + (size_t)(j * 512 + k) * 128 + nn]);
}

// ---------------- PNA aggregation (x4 gather ILP, LDS transpose writes) ----------
// writes A_t k-major: atw[kchunk 0..63][NPAD nodes][4 uints]; kchunk = sec*16 + cbase,
// sections: 0 mean, 1 min, 2 max, 3 std.
__global__ void k_agg(const unsigned* __restrict__ hb2, const int* __restrict__ row_ptr,
                      const int* __restrict__ csr_src, const float* __restrict__ inv_d,
                      unsigned* __restrict__ atw, float* __restrict__ bn_zero) {
    __shared__ unsigned ldsb[16 * 260];   // node stride 260 uints (bank-stagger)
    int tid = threadIdx.x;
    if (blockIdx.x == 0) bn_zero[tid] = 0.f;   // zero bn_sum[128]+bn_sq[128] for next gemm
    int w = tid >> 6, t = tid & 63;
    int node0 = blockIdx.x * 16;
    #pragma unroll 1
    for (int q = 0; q < 4; q++) {
        int nl = w * 4 + q;
        int node = node0 + nl;
        int beg = row_ptr[node], end = row_ptr[node + 1];
        float s1a = 0.f, s1b = 0.f, s2a = 0.f, s2b = 0.f;
        float mna = INFINITY, mnb = INFINITY, mxa = -INFINITY, mxb = -INFINITY;
        int e = beg;
        for (; e + 3 < end; e += 4) {          // 4 independent gathers in flight
            int sa = csr_src[e],     sb = csr_src[e + 1];
            int sc = csr_src[e + 2], sd = csr_src[e + 3];
            unsigned va = hb2[(size_t)sa * 64 + t];
            unsigned vb = hb2[(size_t)sb * 64 + t];
            unsigned vc = hb2[(size_t)sc * 64 + t];
            unsigned vd = hb2[(size_t)sd * 64 + t];
            float a0 = bf_lo(va), b0 = bf_hi(va);
            float a1 = bf_lo(vb), b1 = bf_hi(vb);
            float a2 = bf_lo(vc), b2 = bf_hi(vc);
            float a3 = bf_lo(vd), b3 = bf_hi(vd);
            s1a += (a0 + a1) + (a2 + a3);
            s2a += a0 * a0 + a1 * a1 + a2 * a2 + a3 * a3;
            mna = fminf(fminf(mna, fminf(a0, a1)), fminf(a2, a3));
            mxa = fmaxf(fmaxf(mxa, fmaxf(a0, a1)), fmaxf(a2, a3));
            s1b += (b0 + b1) + (b2 + b3);
            s2b += b0 * b0 + b1 * b1 + b2 * b2 + b3 * b3;
            mnb = fminf(fminf(mnb, fminf(b0, b1)), fminf(b2, b3));
            mxb = fmaxf(fmaxf(mxb, fmaxf(b0, b1)), fmaxf(b2, b3));
        }
        for (; e < end; e++) {
            int sa = csr_src[e];
            unsigned va = hb2[(size_t)sa * 64 + t];
            float a0 = bf_lo(va), b0 = bf_hi(va);
            s1a += a0; s2a += a0 * a0; mna = fminf(mna, a0); mxa = fmaxf(mxa, a0);
            s1b += b0; s2b += b0 * b0; mnb = fminf(mnb, b0); mxb = fmaxf(mxb, b0);
        }
        float id = inv_d[node];
        float meana = s1a * id, meanb = s1b * id;
        float sda = sqrtf(fmaxf(s2a * id - meana * meana, 0.f) + EPSF);
        float sdb = sqrtf(fmaxf(s2b * id - meanb * meanb, 0.f) + EPSF);
        if (beg == end) { mna = 0.f; mxa = 0.f; mnb = 0.f; mxb = 0.f; }
        int base = nl * 260;
        ldsb[base + 0 * 64 + t] = pack_bf2(meana, meanb);
        ldsb[base + 1 * 64 + t] = pack_bf2(mna, mnb);
        ldsb[base + 2 * 64 + t] = pack_bf2(mxa, mxb);
        ldsb[base + 3 * 64 + t] = pack_bf2(sda, sdb);
    }
    __syncthreads();
    // write phase: 64 chunks x 16 nodes x 16B; lanes cover consecutive nodes -> 256B segs
    #pragma unroll
    for (int p = 0; p < 4; p++) {
        int id = p * 256 + tid;
        int node = id & 15, c = id >> 4;
        int sec = c >> 4, cb = c & 15;
        const unsigned* s = &ldsb[node * 260 + sec * 64 + cb * 4];
        uint4 v = make_uint4(s[0], s[1], s[2], s[3]);
        *(uint4*)&atw[((size_t)c * NPAD + node0 + node) * 4] = v;
    }
}

// --- MFMA GEMM v13: zero-barrier, 3-stage register pipeline (2-deep), XCD swizzle ---
// A_t[kc][NPAD][8], Bt2[kc][3][128][8] (fragment lane axis contiguous -> coalesced).
// 256 thr (4 row-waves), tile 256 rows x 32 cols; wave w owns rows [w*64,+64).
// Grid 800 flat: tile=(bid>>5)*8+(bid&7), cg=(bid>>3)&3 -> same-tile blocks share
// bid%8 (same XCD) -> A 1x HBM + 3x L2 (verified r10: FETCH 53->29 MB).
// 3 buffers x 40 VGPR + 96 acc ~= 246/thread -> still 2 waves/SIMD, but prefetch
// distance 2 doubles latency cover to 932 SIMD-cyc/wave (HBM-class).
__global__ __launch_bounds__(256, 2) void k_gemm_mfma(
    const unsigned short* __restrict__ At, const unsigned short* __restrict__ Bt2,
    const float* __restrict__ bias, const float* __restrict__ amp,
    const float* __restrict__ att, float* __restrict__ outp,
    float* __restrict__ bn_sum, float* __restrict__ bn_sq, int n) {
    int tid = threadIdx.x;
    int w = tid >> 6, lane = tid & 63;
    int quad = lane >> 4, l16 = lane & 15;
    int bid = blockIdx.x;
    int tile = (bid >> 5) * 8 + (bid & 7);
    int cg = (bid >> 3) & 3;
    if (tile >= 196) return;
    int c0 = cg * 32;
    int base = tile * 256 + w * 64;

    f32x4 acc[4][2][3];
    #pragma unroll
    for (int rt = 0; rt < 4; rt++)
        #pragma unroll
        for (int ct = 0; ct < 2; ct++)
            #pragma unroll
            for (int j = 0; j < 3; j++) acc[rt][ct][j] = (f32x4)(0.f);

    const unsigned short* pA = At + ((size_t)quad * NPAD + base + l16) * 8;
    const unsigned short* pB = Bt2 + ((size_t)quad * 384 + c0 + l16) * 8;
    const size_t stepA = (size_t)4 * NPAD * 8;
    const int stepB = 4 * 384 * 8;

    bf16x8 af0[4], af1[4], af2[4], bf0[2][3], bf1[2][3], bf2[2][3];
    auto loadA = [&](bf16x8* dst) {
        #pragma unroll
        for (int rt = 0; rt < 4; rt++) dst[rt] = *(const bf16x8*)(pA + rt * 128);
        pA += stepA;
    };
    auto loadB = [&](bf16x8 (*dst)[3]) {
        #pragma unroll
        for (int ct = 0; ct < 2; ct++)
            #pragma unroll
            for (int j = 0; j < 3; j++)
                dst[ct][j] = *(const bf16x8*)(pB + j * 1024 + ct * 128);
        pB += stepB;
    };
    auto domfma = [&](bf16x8* af, bf16x8 (*bf)[3]) {
        #pragma unroll
        for (int ct = 0; ct < 2; ct++)
            #pragma unroll
            for (int j = 0; j < 3; j++)
                #pragma unroll
                for (int rt = 0; rt < 4; rt++)
                    acc[rt][ct][j] = __builtin_amdgcn_mfma_f32_16x16x32_bf16(
                        af[rt], bf[ct][j], acc[rt][ct][j], 0, 0, 0);
    };

    loadA(af0); loadB(bf0);            // iter 0
    loadA(af1); loadB(bf1);            // iter 1
    // 3-stage rotation, prefetch distance 2. 5 x 3 iters + 1 tail = 16 MFMA steps;
    // loads run to iter 16 (pad kchunks 64..67, allocated in At and Bt2 tail).
    #pragma unroll 1
    for (int it = 0; it < 15; it += 3) {
        loadA(af2); loadB(bf2);        // iter it+2
        domfma(af0, bf0);              // iter it
        loadA(af0); loadB(bf0);        // iter it+3
        domfma(af1, bf1);              // iter it+1
        loadA(af1); loadB(bf1);        // iter it+4
        domfma(af2, bf2);              // iter it+2
    }
    domfma(af0, bf0);                  // iter 15

    // epilogue: combine j via amp/att, bias, write, BN partials
    float psum[2] = {0.f, 0.f}, psq[2] = {0.f, 0.f};
    #pragma unroll
    for (int rt = 0; rt < 4; rt++) {
        #pragma unroll
        for (int reg = 0; reg < 4; reg++) {
            int row = base + rt * 16 + quad * 4 + reg;
            if (row < n) {
                float am = amp[row], at = att[row];
                #pragma unroll
                for (int ct = 0; ct < 2; ct++) {
                    int col = c0 + ct * 16 + l16;
                    float v = acc[rt][ct][0][reg] + am * acc[rt][ct][1][reg]
                            + at * acc[rt][ct][2][reg] + bias[col];
                    outp[(size_t)row * DD + col] = v;
                    psum[ct] += v;
                    psq[ct] += v * v;
                }
            }
        }
    }
    #pragma unroll
    for (int ct = 0; ct < 2; ct++) {
        psum[ct] += __shfl_xor(psum[ct], 16, 64);
        psum[ct] += __shfl_xor(psum[ct], 32, 64);
        psq[ct]  += __shfl_xor(psq[ct], 16, 64);
        psq[ct]  += __shfl_xor(psq[ct], 32, 64);
    }
    if (quad == 0) {
        #pragma unroll
        for (int ct = 0; ct < 2; ct++) {
            int col = c0 + ct * 16 + l16;
            atomicAdd(&bn_sum[col], psum[ct]);
            atomicAdd(&bn_sq[col], psq[ct]);
        }
    }
}

// ------- BN stats+apply+relu+residual (bf16 h state only; 8 channels/thread) --------
__global__ void k_bnapply(const float* __restrict__ outp, const float* __restrict__ bn_sum,
                          const float* __restrict__ bn_sq, const float* __restrict__ gamma,
                          const float* __restrict__ beta, unsigned* __restrict__ hb2,
                          int total8) {
    int i = blockIdx.x * blockDim.x + threadIdx.x;
    if (i >= total8) return;
    int c = (i & 15) * 8;
    const float invn = 1.f / (float)NN;
    float4 o0 = ((const float4*)outp)[i * 2];
    float4 o1 = ((const float4*)outp)[i * 2 + 1];
    uint4 hv = ((const uint4*)hb2)[i];
    float oo[8] = {o0.x, o0.y, o0.z, o0.w, o1.x, o1.y, o1.z, o1.w};
    unsigned hu[4] = {hv.x, hv.y, hv.z, hv.w};
    unsigned ru[4];
    #pragma unroll
    for (int p = 0; p < 4; p++) {
        int c0 = c + p * 2;
        float mu0 = bn_sum[c0] * invn;
        float var0 = bn_sq[c0] * invn - mu0 * mu0;
        float sc0 = rsqrtf(var0 + EPSF) * gamma[c0];
        float sh0 = beta[c0] - mu0 * sc0;
        float mu1 = bn_sum[c0 + 1] * invn;
        float var1 = bn_sq[c0 + 1] * invn - mu1 * mu1;
        float sc1 = rsqrtf(var1 + EPSF) * gamma[c0 + 1];
        float sh1 = beta[c0 + 1] - mu1 * sc1;
        float v0 = fmaxf(oo[p * 2] * sc0 + sh0, 0.f) + bf_lo(hu[p]);
        float v1 = fmaxf(oo[p * 2 + 1] * sc1 + sh1, 0.f) + bf_hi(hu[p]);
        ru[p] = pack_bf2(v0, v1);
    }
    ((uint4*)hb2)[i] = make_uint4(ru[0], ru[1], ru[2], ru[3]);
}

// ---------------- pool + MLP (bf16 h input) ----------------
__global__ void k_pool_mlp(const unsigned* __restrict__ hb2, const int* __restrict__ batch,
                           const float* __restrict__ W1, const float* __restrict__ b1,
                           const float* __restrict__ W2, const float* __restrict__ b2,
                           const float* __restrict__ W3, const float* __restrict__ b3,
                           float* __restrict__ out, int n) {
    __shared__ float gvec[128];
    __shared__ float h1[64];
    __shared__ float h2[32];
    __shared__ int srange[2];
    int g = blockIdx.x;
    int t = threadIdx.x;
    if (t < 2) {
        int target = g + t;
        int lo = 0, hi = n;
        while (lo < hi) {
            int mid = (lo + hi) >> 1;
            if (batch[mid] < target) lo = mid + 1; else hi = mid;
        }
        srange[t] = lo;
    }
    __syncthreads();
    int s = srange[0], e = srange[1];
    int p = t >> 1, odd = t & 1;
    float acc = 0.f;
    for (int i = s; i < e; i++) {
        unsigned v = hb2[(size_t)i * 64 + p];
        acc += odd ? bf_hi(v) : bf_lo(v);
    }
    float cnt = fmaxf((float)(e - s), 1.f);
    gvec[t] = acc / cnt;
    __syncthreads();
    if (t < 64) {
        float a = b1[t];
        for (int k = 0; k < 128; k++) a += gvec[k] * W1[k * 64 + t];
        h1[t] = fmaxf(a, 0.f);
    }
    __syncthreads();
    if (t < 32) {
        float a = b2[t];
        for (int k = 0; k < 64; k++) a += h1[k] * W2[k * 32 + t];
        h2[t] = fmaxf(a, 0.f);
    }
    __syncthreads();
    if (t < 10) {
        float a = b3[t];
        for (int k = 0; k < 32; k++) a += h2[k] * W3[k * 10 + t];
        out[g * NT + t] = a;
    }
}

extern "C" void kernel_launch(void* const* d_in, const int* in_sizes, int n_in,
                              void* d_out, int out_size, void* d_ws, size_t ws_size,
                              hipStream_t stream) {
    const float* x      = (const float*)d_in[0];
    const int*   eidx   = (const int*)d_in[1];
    const int*   batch  = (const int*)d_in[2];
    const float* emb_W  = (const float*)d_in[3];
    const float* emb_b  = (const float*)d_in[4];
    const float* conv_W = (const float*)d_in[5];
    const float* conv_b = (const float*)d_in[6];
    const float* bn_g   = (const float*)d_in[7];
    const float* bn_b   = (const float*)d_in[8];
    const float* W1 = (const float*)d_in[9];
    const float* b1 = (const float*)d_in[10];
    const float* W2 = (const float*)d_in[11];
    const float* b2 = (const float*)d_in[12];
    const float* W3 = (const float*)d_in[13];
    const float* b3 = (const float*)d_in[14];
    float* out = (float*)d_out;

    const int* src = eidx;
    const int* dst = eidx + NE;

    char* p = (char*)d_ws;
    auto carve = [&](size_t bytes) {
        void* r = (void*)p;
        p += (bytes + 255) & ~(size_t)255;
        return r;
    };
    int* deg      = (int*)carve(NN * 4);
    int* row_ptr  = (int*)carve((NN + 1) * 4);
    int* cursor   = (int*)carve(NN * 4);
    int* csr_src  = (int*)carve(NE * 4);
    int* part     = (int*)carve(64 * 4);
    int* offs     = (int*)carve(64 * 4);
    float* inv_d  = (float*)carve(NN * 4);
    float* amp    = (float*)carve(NN * 4);
    float* att    = (float*)carve(NN * 4);
    float* dsum   = (float*)carve(4);
    float* bn_sum = (float*)carve(DD * 4);
    float* bn_sq  = (float*)carve(DD * 4);
    unsigned* hb2 = (unsigned*)carve((size_t)NN * 64 * 4);
    unsigned* At  = (unsigned*)carve((size_t)68 * NPAD * 16);   // 64 kchunks + 4 pad
    float* outp   = (float*)carve((size_t)NN * DD * 4);
    unsigned short* Bt2 = (unsigned short*)carve(((size_t)NL * 196608 + 12288) * 2);

    hipMemsetAsync(deg, 0, NN * 4, stream);

    const int NSB = (NN + 1023) / 1024;   // 49 scan blocks
    k_count<<<(NE + 255) / 256, 256, 0, stream>>>(dst, deg, dsum, NE);
    k_scan_part<<<NSB, 256, 0, stream>>>(deg, part, NN);
    k_scan_top<<<1, 64, 0, stream>>>(part, offs, row_ptr, NSB, NN);
    k_scan_apply<<<NSB, 256, 0, stream>>>(deg, offs, row_ptr, cursor, NN);
    k_fill<<<(NE + 255) / 256, 256, 0, stream>>>(src, dst, cursor, csr_src, NE);
    k_delta<<<(NN + 255) / 256, 256, 0, stream>>>(deg, dsum, NN);
    k_scalars<<<(NN + 255) / 256, 256, 0, stream>>>(deg, dsum, inv_d, amp, att, NN);
    k_emb<<<(NN * 64 + 255) / 256, 256, 0, stream>>>(x, emb_W, emb_b, hb2, NN * 64);
    k_wconv<<<(NL * 196608 + 255) / 256, 256, 0, stream>>>(conv_W, Bt2, NL * 196608);

    const int gemm_blocks = 800;   // 25 groups x 32; tile=(bid>>5)*8+(bid&7), cg=(bid>>3)&3
    for (int l = 0; l < NL; l++) {
        k_agg<<<NN / 16, 256, 0, stream>>>(hb2, row_ptr, csr_src, inv_d, At, bn_sum);
        k_gemm_mfma<<<gemm_blocks, 256, 0, stream>>>(
            (const unsigned short*)At, Bt2 + (size_t)l * 196608,
            conv_b + l * DD, amp, att, outp, bn_sum, bn_sq, NN);
        k_bnapply<<<(NN * 16 + 255) / 256, 256, 0, stream>>>(
            outp, bn_sum, bn_sq, bn_g + l * DD, bn_b + l * DD, hb2, NN * 16);
    }

    k_pool_mlp<<<NG, 128, 0, stream>>>(hb2, batch, W1, b1, W2, b2, W3, b3, out, NN);
}

// Round 14
// 567.277 us; speedup vs baseline: 1.4045x; 1.0434x over previous
//
#include <hip/hip_runtime.h>
#include <math.h>

#define NN 50000
#define NE 600000
#define DD 128
#define NL 4
#define NG 512
#define NT 10
#define NPAD 50176          // 392 * 128, padded row count for A_t
#define EPSF 1e-5f

typedef __bf16 bf16x8 __attribute__((ext_vector_type(8)));
typedef float f32x4 __attribute__((ext_vector_type(4)));

__device__ __forceinline__ unsigned short f2bf(float x) {
    union { float f; unsigned u; } v; v.f = x;
    unsigned r = v.u + 0x7FFFu + ((v.u >> 16) & 1u);
    return (unsigned short)(r >> 16);
}
__device__ __forceinline__ unsigned pack_bf2(float a, float b) {
    return (unsigned)f2bf(a) | ((unsigned)f2bf(b) << 16);
}
__device__ __forceinline__ float bf_lo(unsigned v) {
    union { unsigned u; float f; } w; w.u = (v & 0xFFFFu) << 16; return w.f;
}
__device__ __forceinline__ float bf_hi(unsigned v) {
    union { unsigned u; float f; } w; w.u = v & 0xFFFF0000u; return w.f;
}

// ---------------- CSR build ----------------
__global__ void k_count(const int* __restrict__ dst, int* __restrict__ deg,
                        float* __restrict__ dsum, int E) {
    int e = blockIdx.x * blockDim.x + threadIdx.x;
    if (e == 0) *dsum = 0.f;
    if (e < E) atomicAdd(&deg[dst[e]], 1);
}

__global__ void k_scan_part(const int* __restrict__ deg, int* __restrict__ part, int n) {
    __shared__ int sm[256];
    int b = blockIdx.x, t = threadIdx.x;
    int base = b * 1024 + t * 4;
    int s = 0;
    #pragma unroll
    for (int j = 0; j < 4; j++) if (base + j < n) s += deg[base + j];
    sm[t] = s;
    __syncthreads();
    for (int off = 128; off > 0; off >>= 1) {
        if (t < off) sm[t] += sm[t + off];
        __syncthreads();
    }
    if (t == 0) part[b] = sm[0];
}

__global__ void k_scan_top(const int* __restrict__ part, int* __restrict__ offs,
                           int* __restrict__ row_ptr, int nb, int n) {
    if (threadIdx.x == 0) {
        int acc = 0;
        for (int i = 0; i < nb; i++) { offs[i] = acc; acc += part[i]; }
        row_ptr[n] = acc;
    }
}

__global__ void k_scan_apply(const int* __restrict__ deg, const int* __restrict__ offs,
                             int* __restrict__ row_ptr, int* __restrict__ cursor, int n) {
    __shared__ int sm[256];
    int b = blockIdx.x, t = threadIdx.x;
    int base = b * 1024 + t * 4;
    int v[4]; int s = 0;
    #pragma unroll
    for (int j = 0; j < 4; j++) { v[j] = (base + j < n) ? deg[base + j] : 0; s += v[j]; }
    sm[t] = s;
    __syncthreads();
    for (int off = 1; off < 256; off <<= 1) {
        int y = (t >= off) ? sm[t - off] : 0;
        __syncthreads();
        sm[t] += y;
        __syncthreads();
    }
    int run = offs[b] + sm[t] - s;
    #pragma unroll
    for (int j = 0; j < 4; j++) {
        if (base + j < n) { row_ptr[base + j] = run; cursor[base + j] = run; run += v[j]; }
    }
}

__global__ void k_fill(const int* __restrict__ src, const int* __restrict__ dst,
                       int* __restrict__ cursor, int* __restrict__ csr_src, int E) {
    int e = blockIdx.x * blockDim.x + threadIdx.x;
    if (e < E) {
        int d = dst[e];
        int pos = atomicAdd(&cursor[d], 1);
        csr_src[pos] = src[e];
    }
}

// ---------------- degree scalars ----------------
__global__ void k_delta(const int* __restrict__ deg, float* __restrict__ dsum, int n) {
    int i = blockIdx.x * blockDim.x + threadIdx.x;
    float v = (i < n) ? log1pf((float)deg[i]) : 0.f;
    #pragma unroll
    for (int off = 32; off > 0; off >>= 1) v += __shfl_down(v, off);
    if ((threadIdx.x & 63) == 0) atomicAdd(dsum, v);
}

__global__ void k_scalars(const int* __restrict__ deg, const float* __restrict__ dsum,
                          float* __restrict__ inv_d, float* __restrict__ amp,
                          float* __restrict__ att, int n) {
    int i = blockIdx.x * blockDim.x + threadIdx.x;
    if (i >= n) return;
    float delta = *dsum / (float)n;
    float d = fmaxf((float)deg[i], 1.f);
    float ld = log1pf(d);
    inv_d[i] = 1.f / d;
    amp[i] = ld / delta;
    att[i] = delta / ld;
}

// ---------------- node embedding (bf16 h only) ----------------
__global__ void k_emb(const float* __restrict__ x, const float* __restrict__ W,
                      const float* __restrict__ b, unsigned* __restrict__ hb2, int total2) {
    int i = blockIdx.x * blockDim.x + threadIdx.x;
    if (i >= total2) return;
    int node = i >> 6, c = (i & 63) * 2;
    float x0 = x[node * 3 + 0], x1 = x[node * 3 + 1], x2 = x[node * 3 + 2];
    float v0 = x0 * W[c] + x1 * W[DD + c] + x2 * W[2 * DD + c] + b[c];
    float v1 = x0 * W[c + 1] + x1 * W[DD + c + 1] + x2 * W[2 * DD + c + 1] + b[c + 1];
    hb2[i] = pack_bf2(v0, v1);
}

// -------- weight convert: conv_W [L,1536,128] f32 -> Bt2 [L][64 kc][3 j][128 col][8] bf16 ----
__global__ void k_wconv(const float* __restrict__ W, unsigned short* __restrict__ Bt2, int total) {
    int o = blockIdx.x * blockDim.x + threadIdx.x;
    if (o >= total) return;
    int l = o / 196608;
    int idx = o % 196608;
    int kc = idx / 3072;
    int rem = idx % 3072;
    int j = rem >> 10;
    int nn = (rem >> 3) & 127;
    int k8 = rem & 7;
    int k = kc * 8 + k8;
    Bt2[o] = f2bf(W[(size_t)l * 196608 + (size_t)(j * 512 + k) * 128 + nn]);
}

// ------ PNA aggregation v14: node-pair interleave (8 gathers in flight) ------
// writes A_t k-major: atw[kchunk 0..63][NPAD nodes][4 uints]; kchunk = sec*16 + cbase.
// Wave w owns nodes [node0+4w, +4) as 2 concurrent pairs; main loop issues 4 gathers
// for EACH node of the pair before accumulating -> 8 independent loads in flight
// (2x MLP vs r10). Bounds are wave-uniform -> s_cbranch, no lane divergence.
__global__ void k_agg(const unsigned* __restrict__ hb2, const int* __restrict__ row_ptr,
                      const int* __restrict__ csr_src, const float* __restrict__ inv_d,
                      unsigned* __restrict__ atw, float* __restrict__ bn_zero) {
    __shared__ unsigned ldsb[16 * 260];   // node stride 260 uints (bank-stagger)
    int tid = threadIdx.x;
    if (blockIdx.x == 0) bn_zero[tid] = 0.f;   // zero bn_sum[128]+bn_sq[128] for next gemm
    int w = tid >> 6, t = tid & 63;
    int node0 = blockIdx.x * 16;

    #pragma unroll 1
    for (int pp = 0; pp < 2; pp++) {
        int nlA = w * 4 + pp * 2;
        int nodeA = node0 + nlA, nodeB = nodeA + 1;
        int bgA = row_ptr[nodeA], enA = row_ptr[nodeA + 1];
        int bgB = row_ptr[nodeB], enB = row_ptr[nodeB + 1];
        float s1[2][2] = {{0.f,0.f},{0.f,0.f}};
        float s2[2][2] = {{0.f,0.f},{0.f,0.f}};
        float mn[2][2] = {{INFINITY,INFINITY},{INFINITY,INFINITY}};
        float mx[2][2] = {{-INFINITY,-INFINITY},{-INFINITY,-INFINITY}};
        auto ACC = [&](int ns, unsigned v) {
            float a = bf_lo(v), b = bf_hi(v);
            s1[ns][0] += a; s2[ns][0] += a * a;
            mn[ns][0] = fminf(mn[ns][0], a); mx[ns][0] = fmaxf(mx[ns][0], a);
            s1[ns][1] += b; s2[ns][1] += b * b;
            mn[ns][1] = fminf(mn[ns][1], b); mx[ns][1] = fmaxf(mx[ns][1], b);
        };
        int ea = bgA, eb = bgB;
        // paired main loop: 8 gathers in flight
        while (ea + 3 < enA && eb + 3 < enB) {
            int ia0 = csr_src[ea],     ia1 = csr_src[ea + 1];
            int ia2 = csr_src[ea + 2], ia3 = csr_src[ea + 3];
            int ib0 = csr_src[eb],     ib1 = csr_src[eb + 1];
            int ib2 = csr_src[eb + 2], ib3 = csr_src[eb + 3];
            unsigned va0 = hb2[(size_t)ia0 * 64 + t];
            unsigned va1 = hb2[(size_t)ia1 * 64 + t];
            unsigned va2 = hb2[(size_t)ia2 * 64 + t];
            unsigned va3 = hb2[(size_t)ia3 * 64 + t];
            unsigned vb0 = hb2[(size_t)ib0 * 64 + t];
            unsigned vb1 = hb2[(size_t)ib1 * 64 + t];
            unsigned vb2 = hb2[(size_t)ib2 * 64 + t];
            unsigned vb3 = hb2[(size_t)ib3 * 64 + t];
            ACC(0, va0); ACC(0, va1); ACC(0, va2); ACC(0, va3);
            ACC(1, vb0); ACC(1, vb1); ACC(1, vb2); ACC(1, vb3);
            ea += 4; eb += 4;
        }
        // drain node A
        for (; ea + 3 < enA; ea += 4) {
            int i0 = csr_src[ea], i1 = csr_src[ea + 1];
            int i2 = csr_src[ea + 2], i3 = csr_src[ea + 3];
            unsigned v0 = hb2[(size_t)i0 * 64 + t];
            unsigned v1 = hb2[(size_t)i1 * 64 + t];
            unsigned v2 = hb2[(size_t)i2 * 64 + t];
            unsigned v3 = hb2[(size_t)i3 * 64 + t];
            ACC(0, v0); ACC(0, v1); ACC(0, v2); ACC(0, v3);
        }
        for (; ea < enA; ea++) ACC(0, hb2[(size_t)csr_src[ea] * 64 + t]);
        // drain node B
        for (; eb + 3 < enB; eb += 4) {
            int i0 = csr_src[eb], i1 = csr_src[eb + 1];
            int i2 = csr_src[eb + 2], i3 = csr_src[eb + 3];
            unsigned v0 = hb2[(size_t)i0 * 64 + t];
            unsigned v1 = hb2[(size_t)i1 * 64 + t];
            unsigned v2 = hb2[(size_t)i2 * 64 + t];
            unsigned v3 = hb2[(size_t)i3 * 64 + t];
            ACC(1, v0); ACC(1, v1); ACC(1, v2); ACC(1, v3);
        }
        for (; eb < enB; eb++) ACC(1, hb2[(size_t)csr_src[eb] * 64 + t]);

        // finalize + LDS store
        #pragma unroll
        for (int ns = 0; ns < 2; ns++) {
            int node = (ns == 0) ? nodeA : nodeB;
            int nl = nlA + ns;
            int bg = (ns == 0) ? bgA : bgB;
            int en = (ns == 0) ? enA : enB;
            float id = inv_d[node];
            float meana = s1[ns][0] * id, meanb = s1[ns][1] * id;
            float sda = sqrtf(fmaxf(s2[ns][0] * id - meana * meana, 0.f) + EPSF);
            float sdb = sqrtf(fmaxf(s2[ns][1] * id - meanb * meanb, 0.f) + EPSF);
            float mna = mn[ns][0], mnb = mn[ns][1];
            float mxa = mx[ns][0], mxb = mx[ns][1];
            if (bg == en) { mna = 0.f; mxa = 0.f; mnb = 0.f; mxb = 0.f; }
            int base = nl * 260;
            ldsb[base + 0 * 64 + t] = pack_bf2(meana, meanb);
            ldsb[base + 1 * 64 + t] = pack_bf2(mna, mnb);
            ldsb[base + 2 * 64 + t] = pack_bf2(mxa, mxb);
            ldsb[base + 3 * 64 + t] = pack_bf2(sda, sdb);
        }
    }
    __syncthreads();
    // write phase: 64 chunks x 16 nodes x 16B; lanes cover consecutive nodes -> 256B segs
    #pragma unroll
    for (int p = 0; p < 4; p++) {
        int id = p * 256 + tid;
        int node = id & 15, c = id >> 4;
        int sec = c >> 4, cb = c & 15;
        const unsigned* s = &ldsb[node * 260 + sec * 64 + cb * 4];
        uint4 v = make_uint4(s[0], s[1], s[2], s[3]);
        *(uint4*)&atw[((size_t)c * NPAD + node0 + node) * 4] = v;
    }
}

// --- MFMA GEMM v13: zero-barrier, 3-stage register pipeline (2-deep), XCD swizzle ---
__global__ __launch_bounds__(256, 2) void k_gemm_mfma(
    const unsigned short* __restrict__ At, const unsigned short* __restrict__ Bt2,
    const float* __restrict__ bias, const float* __restrict__ amp,
    const float* __restrict__ att, float* __restrict__ outp,
    float* __restrict__ bn_sum, float* __restrict__ bn_sq, int n) {
    int tid = threadIdx.x;
    int w = tid >> 6, lane = tid & 63;
    int quad = lane >> 4, l16 = lane & 15;
    int bid = blockIdx.x;
    int tile = (bid >> 5) * 8 + (bid & 7);
    int cg = (bid >> 3) & 3;
    if (tile >= 196) return;
    int c0 = cg * 32;
    int base = tile * 256 + w * 64;

    f32x4 acc[4][2][3];
    #pragma unroll
    for (int rt = 0; rt < 4; rt++)
        #pragma unroll
        for (int ct = 0; ct < 2; ct++)
            #pragma unroll
            for (int j = 0; j < 3; j++) acc[rt][ct][j] = (f32x4)(0.f);

    const unsigned short* pA = At + ((size_t)quad * NPAD + base + l16) * 8;
    const unsigned short* pB = Bt2 + ((size_t)quad * 384 + c0 + l16) * 8;
    const size_t stepA = (size_t)4 * NPAD * 8;
    const int stepB = 4 * 384 * 8;

    bf16x8 af0[4], af1[4], af2[4], bf0[2][3], bf1[2][3], bf2[2][3];
    auto loadA = [&](bf16x8* dst) {
        #pragma unroll
        for (int rt = 0; rt < 4; rt++) dst[rt] = *(const bf16x8*)(pA + rt * 128);
        pA += stepA;
    };
    auto loadB = [&](bf16x8 (*dst)[3]) {
        #pragma unroll
        for (int ct = 0; ct < 2; ct++)
            #pragma unroll
            for (int j = 0; j < 3; j++)
                dst[ct][j] = *(const bf16x8*)(pB + j * 1024 + ct * 128);
        pB += stepB;
    };
    auto domfma = [&](bf16x8* af, bf16x8 (*bf)[3]) {
        #pragma unroll
        for (int ct = 0; ct < 2; ct++)
            #pragma unroll
            for (int j = 0; j < 3; j++)
                #pragma unroll
                for (int rt = 0; rt < 4; rt++)
                    acc[rt][ct][j] = __builtin_amdgcn_mfma_f32_16x16x32_bf16(
                        af[rt], bf[ct][j], acc[rt][ct][j], 0, 0, 0);
    };

    loadA(af0); loadB(bf0);            // iter 0
    loadA(af1); loadB(bf1);            // iter 1
    #pragma unroll 1
    for (int it = 0; it < 15; it += 3) {
        loadA(af2); loadB(bf2);        // iter it+2
        domfma(af0, bf0);              // iter it
        loadA(af0); loadB(bf0);        // iter it+3
        domfma(af1, bf1);              // iter it+1
        loadA(af1); loadB(bf1);        // iter it+4
        domfma(af2, bf2);              // iter it+2
    }
    domfma(af0, bf0);                  // iter 15

    // epilogue: combine j via amp/att, bias, write, BN partials
    float psum[2] = {0.f, 0.f}, psq[2] = {0.f, 0.f};
    #pragma unroll
    for (int rt = 0; rt < 4; rt++) {
        #pragma unroll
        for (int reg = 0; reg < 4; reg++) {
            int row = base + rt * 16 + quad * 4 + reg;
            if (row < n) {
                float am = amp[row], at = att[row];
                #pragma unroll
                for (int ct = 0; ct < 2; ct++) {
                    int col = c0 + ct * 16 + l16;
                    float v = acc[rt][ct][0][reg] + am * acc[rt][ct][1][reg]
                            + at * acc[rt][ct][2][reg] + bias[col];
                    outp[(size_t)row * DD + col] = v;
                    psum[ct] += v;
                    psq[ct] += v * v;
                }
            }
        }
    }
    #pragma unroll
    for (int ct = 0; ct < 2; ct++) {
        psum[ct] += __shfl_xor(psum[ct], 16, 64);
        psum[ct] += __shfl_xor(psum[ct], 32, 64);
        psq[ct]  += __shfl_xor(psq[ct], 16, 64);
        psq[ct]  += __shfl_xor(psq[ct], 32, 64);
    }
    if (quad == 0) {
        #pragma unroll
        for (int ct = 0; ct < 2; ct++) {
            int col = c0 + ct * 16 + l16;
            atomicAdd(&bn_sum[col], psum[ct]);
            atomicAdd(&bn_sq[col], psq[ct]);
        }
    }
}

// ------- BN stats+apply+relu+residual (bf16 h state only; 8 channels/thread) --------
__global__ void k_bnapply(const float* __restrict__ outp, const float* __restrict__ bn_sum,
                          const float* __restrict__ bn_sq, const float* __restrict__ gamma,
                          const float* __restrict__ beta, unsigned* __restrict__ hb2,
                          int total8) {
    int i = blockIdx.x * blockDim.x + threadIdx.x;
    if (i >= total8) return;
    int c = (i & 15) * 8;
    const float invn = 1.f / (float)NN;
    float4 o0 = ((const float4*)outp)[i * 2];
    float4 o1 = ((const float4*)outp)[i * 2 + 1];
    uint4 hv = ((const uint4*)hb2)[i];
    float oo[8] = {o0.x, o0.y, o0.z, o0.w, o1.x, o1.y, o1.z, o1.w};
    unsigned hu[4] = {hv.x, hv.y, hv.z, hv.w};
    unsigned ru[4];
    #pragma unroll
    for (int p = 0; p < 4; p++) {
        int c0 = c + p * 2;
        float mu0 = bn_sum[c0] * invn;
        float var0 = bn_sq[c0] * invn - mu0 * mu0;
        float sc0 = rsqrtf(var0 + EPSF) * gamma[c0];
        float sh0 = beta[c0] - mu0 * sc0;
        float mu1 = bn_sum[c0 + 1] * invn;
        float var1 = bn_sq[c0 + 1] * invn - mu1 * mu1;
        float sc1 = rsqrtf(var1 + EPSF) * gamma[c0 + 1];
        float sh1 = beta[c0 + 1] - mu1 * sc1;
        float v0 = fmaxf(oo[p * 2] * sc0 + sh0, 0.f) + bf_lo(hu[p]);
        float v1 = fmaxf(oo[p * 2 + 1] * sc1 + sh1, 0.f) + bf_hi(hu[p]);
        ru[p] = pack_bf2(v0, v1);
    }
    ((uint4*)hb2)[i] = make_uint4(ru[0], ru[1], ru[2], ru[3]);
}

// ---------------- pool + MLP (bf16 h input) ----------------
__global__ void k_pool_mlp(const unsigned* __restrict__ hb2, const int* __restrict__ batch,
                           const float* __restrict__ W1, const float* __restrict__ b1,
                           const float* __restrict__ W2, const float* __restrict__ b2,
                           const float* __restrict__ W3, const float* __restrict__ b3,
                           float* __restrict__ out, int n) {
    __shared__ float gvec[128];
    __shared__ float h1[64];
    __shared__ float h2[32];
    __shared__ int srange[2];
    int g = blockIdx.x;
    int t = threadIdx.x;
    if (t < 2) {
        int target = g + t;
        int lo = 0, hi = n;
        while (lo < hi) {
            int mid = (lo + hi) >> 1;
            if (batch[mid] < target) lo = mid + 1; else hi = mid;
        }
        srange[t] = lo;
    }
    __syncthreads();
    int s = srange[0], e = srange[1];
    int p = t >> 1, odd = t & 1;
    float acc = 0.f;
    for (int i = s; i < e; i++) {
        unsigned v = hb2[(size_t)i * 64 + p];
        acc += odd ? bf_hi(v) : bf_lo(v);
    }
    float cnt = fmaxf((float)(e - s), 1.f);
    gvec[t] = acc / cnt;
    __syncthreads();
    if (t < 64) {
        float a = b1[t];
        for (int k = 0; k < 128; k++) a += gvec[k] * W1[k * 64 + t];
        h1[t] = fmaxf(a, 0.f);
    }
    __syncthreads();
    if (t < 32) {
        float a = b2[t];
        for (int k = 0; k < 64; k++) a += h1[k] * W2[k * 32 + t];
        h2[t] = fmaxf(a, 0.f);
    }
    __syncthreads();
    if (t < 10) {
        float a = b3[t];
        for (int k = 0; k < 32; k++) a += h2[k] * W3[k * 10 + t];
        out[g * NT + t] = a;
    }
}

extern "C" void kernel_launch(void* const* d_in, const int* in_sizes, int n_in,
                              void* d_out, int out_size, void* d_ws, size_t ws_size,
                              hipStream_t stream) {
    const float* x      = (const float*)d_in[0];
    const int*   eidx   = (const int*)d_in[1];
    const int*   batch  = (const int*)d_in[2];
    const float* emb_W  = (const float*)d_in[3];
    const float* emb_b  = (const float*)d_in[4];
    const float* conv_W = (const float*)d_in[5];
    const float* conv_b = (const float*)d_in[6];
    const float* bn_g   = (const float*)d_in[7];
    const float* bn_b   = (const float*)d_in[8];
    const float* W1 = (const float*)d_in[9];
    const float* b1 = (const float*)d_in[10];
    const float* W2 = (const float*)d_in[11];
    const float* b2 = (const float*)d_in[12];
    const float* W3 = (const float*)d_in[13];
    const float* b3 = (const float*)d_in[14];
    float* out = (float*)d_out;

    const int* src = eidx;
    const int* dst = eidx + NE;

    char* p = (char*)d_ws;
    auto carve = [&](size_t bytes) {
        void* r = (void*)p;
        p += (bytes + 255) & ~(size_t)255;
        return r;
    };
    int* deg      = (int*)carve(NN * 4);
    int* row_ptr  = (int*)carve((NN + 1) * 4);
    int* cursor   = (int*)carve(NN * 4);
    int* csr_src  = (int*)carve(NE * 4);
    int* part     = (int*)carve(64 * 4);
    int* offs     = (int*)carve(64 * 4);
    float* inv_d  = (float*)carve(NN * 4);
    float* amp    = (float*)carve(NN * 4);
    float* att    = (float*)carve(NN * 4);
    float* dsum   = (float*)carve(4);
    float* bn_sum = (float*)carve(DD * 4);
    float* bn_sq  = (float*)carve(DD * 4);
    unsigned* hb2 = (unsigned*)carve((size_t)NN * 64 * 4);
    unsigned* At  = (unsigned*)carve((size_t)68 * NPAD * 16);   // 64 kchunks + 4 pad
    float* outp   = (float*)carve((size_t)NN * DD * 4);
    unsigned short* Bt2 = (unsigned short*)carve(((size_t)NL * 196608 + 12288) * 2);

    hipMemsetAsync(deg, 0, NN * 4, stream);

    const int NSB = (NN + 1023) / 1024;   // 49 scan blocks
    k_count<<<(NE + 255) / 256, 256, 0, stream>>>(dst, deg, dsum, NE);
    k_scan_part<<<NSB, 256, 0, stream>>>(deg, part, NN);
    k_scan_top<<<1, 64, 0, stream>>>(part, offs, row_ptr, NSB, NN);
    k_scan_apply<<<NSB, 256, 0, stream>>>(deg, offs, row_ptr, cursor, NN);
    k_fill<<<(NE + 255) / 256, 256, 0, stream>>>(src, dst, cursor, csr_src, NE);
    k_delta<<<(NN + 255) / 256, 256, 0, stream>>>(deg, dsum, NN);
    k_scalars<<<(NN + 255) / 256, 256, 0, stream>>>(deg, dsum, inv_d, amp, att, NN);
    k_emb<<<(NN * 64 + 255) / 256, 256, 0, stream>>>(x, emb_W, emb_b, hb2, NN * 64);
    k_wconv<<<(NL * 196608 + 255) / 256, 256, 0, stream>>>(conv_W, Bt2, NL * 196608);

    const int gemm_blocks = 800;   // 25 groups x 32; tile=(bid>>5)*8+(bid&7), cg=(bid>>3)&3
    for (int l = 0; l < NL; l++) {
        k_agg<<<NN / 16, 256, 0, stream>>>(hb2, row_ptr, csr_src, inv_d, At, bn_sum);
        k_gemm_mfma<<<gemm_blocks, 256, 0, stream>>>(
            (const unsigned short*)At, Bt2 + (size_t)l * 196608,
            conv_b + l * DD, amp, att, outp, bn_sum, bn_sq, NN);
        k_bnapply<<<(NN * 16 + 255) / 256, 256, 0, stream>>>(
            outp, bn_sum, bn_sq, bn_g + l * DD, bn_b + l * DD, hb2, NN * 16);
    }

    k_pool_mlp<<<NG, 128, 0, stream>>>(hb2, batch, W1, b1, W2, b2, W3, b3, out, NN);
}